// Round 19
// baseline (119.910 us; speedup 1.0000x reference)
//
#include <hip/hip_runtime.h>
#include <hip/hip_bf16.h>

#define N_NODES 50000
#define DIM 128
#define N_EDGES 800000
#define NBUCKETS 196      // ceil(50000/256) nodes>>8 buckets
#define BINA_EPB 4096     // edges per binning block
#define NBLKA 196         // ceil(800000/4096) binning blocks
#define SEGCAP 64         // per-(block,bucket) segment capacity (mean 21, sigma 4.6)
#define BSTRIDE_U32 16384 // per-bucket tmp stride in u32 (65536 B)
#define BUCKET_CAP 6144   // per-bucket capacity in sorted (mean 4082, sigma ~64)
#define LN_BLOCKS 12500   // N_NODES/4
#define PLANE_U32 (N_NODES * 16)  // one 32-col plane: 50000 * 64 B = 3.2 MB
#define PLANE_U2  (N_NODES * 8)   // same plane in uint2 units
#define NGROUPS 1563      // ceil(50000/32) node groups for k_gcs

typedef __bf16 bf16_t;
typedef bf16_t bf16x2 __attribute__((ext_vector_type(2)));
typedef bf16_t bf16x4 __attribute__((ext_vector_type(4)));
typedef bf16_t bf16x8 __attribute__((ext_vector_type(8)));
typedef float f32x4 __attribute__((ext_vector_type(4)));

__device__ __forceinline__ float bf_lo(unsigned int u) {
  return __uint_as_float(u << 16);
}
__device__ __forceinline__ float bf_hi(unsigned int u) {
  return __uint_as_float(u & 0xffff0000u);
}

// ------- Kernel 1: binA (0..195) | W->bf16 (196..203) | LayerNorm ---------
// LN writes h in QUARTER-PLANE layout: plane q holds cols [32q,32q+32) of
// all nodes (3.2 MB per plane -> fits one XCD's 4 MB L2).
__global__ __launch_bounds__(256) void k_ln_binA(
    const float* __restrict__ x, const float* __restrict__ gamma,
    const float* __restrict__ beta, bf16_t* __restrict__ hq,
    const int* __restrict__ erows, const int* __restrict__ ecols,
    unsigned int* __restrict__ tmp, int* __restrict__ cnt,
    const float* __restrict__ W1, const float* __restrict__ W2,
    bf16_t* __restrict__ W1b, bf16_t* __restrict__ W2b) {
  __shared__ int sh_hist[256];
  __shared__ int sh_cur[256];
  const int t = threadIdx.x;

  if (blockIdx.x < NBLKA) {
    // ---- binning path ----
    const int blk = blockIdx.x;
    sh_hist[t] = 0;
    __syncthreads();
    const int base = blk * BINA_EPB;
    int bkt[16];
    unsigned int pk[16];
#pragma unroll
    for (int i = 0; i < 16; ++i) {
      const int e = base + i * 256 + t;
      if (e < N_EDGES) {
        const int d = erows[e];
        bkt[i] = d >> 8;
        pk[i] = ((unsigned int)(d & 255) << 16) | (unsigned int)ecols[e];
        atomicAdd(&sh_hist[bkt[i]], 1);
      } else {
        bkt[i] = -1;
      }
    }
    __syncthreads();
    if (t < NBUCKETS) cnt[t * NBLKA + blk] = min(sh_hist[t], SEGCAP);
    sh_cur[t] = 0;
    __syncthreads();
#pragma unroll
    for (int i = 0; i < 16; ++i) {
      if (bkt[i] >= 0) {
        const int pos = atomicAdd(&sh_cur[bkt[i]], 1);
        if (pos < SEGCAP)
          tmp[(size_t)bkt[i] * BSTRIDE_U32 + blk * SEGCAP + pos] = pk[i];
      }
    }
    return;
  }

  if (blockIdx.x < NBLKA + 8) {
    // ---- weight fp32 -> bf16 conversion (W1: 4 blocks, W2: 4 blocks) ----
    const int wid = blockIdx.x - NBLKA;
    const float* src = (wid < 4) ? W1 : W2;
    bf16_t* dst = (wid < 4) ? W1b : W2b;
    const int off = (wid & 3) * 4096 + t * 16;
#pragma unroll
    for (int k = 0; k < 16; k += 4) {
      const float4 u = *(const float4*)(src + off + k);
      *(bf16x4*)(dst + off + k) =
          (bf16x4){(bf16_t)u.x, (bf16_t)u.y, (bf16_t)u.z, (bf16_t)u.w};
    }
    return;
  }

  // ---- LayerNorm path ----
  const int lane = t & 63;
  const int row  = (blockIdx.x - NBLKA - 8) * 4 + (t >> 6);
  const float2 v = *(const float2*)(x + (size_t)row * DIM + lane * 2);
  float s  = v.x + v.y;
  float ss = v.x * v.x + v.y * v.y;
#pragma unroll
  for (int d = 1; d < 64; d <<= 1) {
    s  += __shfl_xor(s, d);
    ss += __shfl_xor(ss, d);
  }
  const float mu   = s * (1.0f / 128.0f);
  const float var  = ss * (1.0f / 128.0f) - mu * mu;
  const float rstd = rsqrtf(var + 1e-5f);
  const float2 g = *(const float2*)(gamma + lane * 2);
  const float2 b = *(const float2*)(beta + lane * 2);
  const float h0 = (v.x - mu) * rstd * g.x + b.x;
  const float h1 = (v.y - mu) * rstd * g.y + b.y;
  // quarter-plane write: lane covers cols {2*lane, 2*lane+1} -> plane lane>>4
  const int q = lane >> 4, cp = lane & 15;
  *(bf16x2*)(hq + 2 * ((size_t)q * PLANE_U32 + row * 16 + cp)) =
      (bf16x2){(bf16_t)h0, (bf16_t)h1};
}

// ------- Kernel 2: within-bucket placement -> nstart/nend + sorted(u16) ---
__global__ __launch_bounds__(256) void k_binB(
    const unsigned int* __restrict__ tmp, const int* __restrict__ cnt,
    int* __restrict__ nstart, int* __restrict__ nend,
    unsigned short* __restrict__ sorted) {
  __shared__ unsigned int stage[BUCKET_CAP];
  __shared__ int sh_cnt[256];
  __shared__ int sh_cur[256];
  __shared__ int wsum[4];
  const int b = blockIdx.x, t = threadIdx.x;
  const int lane = t & 63, w = t >> 6;

  // segment counts + exclusive scan -> stage offsets
  const int c = (t < NBLKA) ? cnt[b * NBLKA + t] : 0;
  int v = c;
#pragma unroll
  for (int d = 1; d < 64; d <<= 1) {
    const int n = __shfl_up(v, d);
    if (lane >= d) v += n;
  }
  if (lane == 63) wsum[w] = v;
  __syncthreads();
  int woff = 0;
  for (int k = 0; k < w; ++k) woff += wsum[k];
  const int soff = v + woff - c;
  int total = wsum[0] + wsum[1] + wsum[2] + wsum[3];
  if (total > BUCKET_CAP) total = BUCKET_CAP;

  // stage this bucket's edges into LDS
  if (c > 0) {
    const unsigned int* seg = tmp + (size_t)b * BSTRIDE_U32 + t * SEGCAP;
    for (int j = 0; j < c; ++j) {
      const int p = soff + j;
      if (p < BUCKET_CAP) stage[p] = seg[j];
    }
  }
  __syncthreads();

  // per-node histogram
  sh_cnt[t] = 0;
  __syncthreads();
  for (int e = t; e < total; e += 256)
    atomicAdd(&sh_cnt[stage[e] >> 16], 1);
  __syncthreads();

  // per-node exclusive scan -> starts
  const int val = sh_cnt[t];
  int v2 = val;
#pragma unroll
  for (int d = 1; d < 64; d <<= 1) {
    const int n = __shfl_up(v2, d);
    if (lane >= d) v2 += n;
  }
  __syncthreads();
  if (lane == 63) wsum[w] = v2;
  __syncthreads();
  int woff2 = 0;
  for (int k = 0; k < w; ++k) woff2 += wsum[k];
  const int rs = b * BUCKET_CAP;
  const int st = rs + v2 + woff2 - val;
  const int nidx = b * 256 + t;
  if (nidx < N_NODES) { nstart[nidx] = st; nend[nidx] = st + val; }
  sh_cur[t] = st;
  __syncthreads();

  // place
  for (int e = t; e < total; e += 256) {
    const unsigned int pv = stage[e];
    const int pos = atomicAdd(&sh_cur[pv >> 16], 1);
    sorted[pos] = (unsigned short)(pv & 0xffffu);
  }
}

// ------- Kernel 3: column-split gather -> acc (bf16, row-major) -----------
// 6256 blocks x 256 threads, NO LDS. plane = (bid%8)>>1 -> plane p runs
// only on XCDs {2p,2p+1} (confirmed: FETCH 95->24 MB in r18). Lean inner
// loop: 8 lanes/edge x uint2 (8 B), 16 edges per {2 shfl + 2 addr + 2
// loads + 4 f32x4 accums}; u32 index math (SGPR-base addressing);
// unmasked main loop + single masked tail iteration.
__global__ __launch_bounds__(256) void k_gcs(
    const uint2* __restrict__ hq2, const int* __restrict__ nstart,
    const int* __restrict__ nend, const unsigned short* __restrict__ sorted,
    const float* __restrict__ epsp, bf16_t* __restrict__ acc) {
  const int bid = blockIdx.x;
  const int plane = (bid & 7) >> 1;
  const int ng = (bid >> 3) * 2 + (bid & 1);
  if (ng >= NGROUPS) return;
  const int t = threadIdx.x, lane = t & 63, w = t >> 6;
  const int ed = lane >> 3, c8 = lane & 7;
  const uint2* hp2 = hq2 + (size_t)plane * PLANE_U2;
  const float epv = 1.0f + epsp[0];
  const int nb = ng * 32 + w * 8;
  for (int i = 0; i < 8; ++i) {
    const int node = nb + i;
    if (node >= N_NODES) break;
    const int s = nstart[node], e = nend[node];
    f32x4 acc0 = {0.f, 0.f, 0.f, 0.f};
    f32x4 acc1 = {0.f, 0.f, 0.f, 0.f};
    for (int base = s; base < e; base += 64) {
      const int cnt2 = e - base;
      const int m = cnt2 < 64 ? cnt2 : 64;
      const int myidx = (lane < m) ? (int)sorted[base + lane] : 0;
      int j = 0;
      for (; j + 16 <= m; j += 16) {
        const unsigned s0 = (unsigned)__shfl(myidx, j + ed);
        const unsigned s1 = (unsigned)__shfl(myidx, j + 8 + ed);
        const uint2 v0 = hp2[s0 * 8u + c8];
        const uint2 v1 = hp2[s1 * 8u + c8];
        acc0 += (f32x4){bf_lo(v0.x), bf_hi(v0.x), bf_lo(v0.y), bf_hi(v0.y)};
        acc1 += (f32x4){bf_lo(v1.x), bf_hi(v1.x), bf_lo(v1.y), bf_hi(v1.y)};
      }
      if (j < m) {
        const int o0 = j + ed, o1 = j + 8 + ed;
        const unsigned s0 = (unsigned)__shfl(myidx, o0);
        const unsigned s1 = (unsigned)__shfl(myidx, o1);
        uint2 v0 = hp2[s0 * 8u + c8];
        uint2 v1 = hp2[s1 * 8u + c8];
        if (o0 >= m) { v0.x = 0u; v0.y = 0u; }
        if (o1 >= m) { v1.x = 0u; v1.y = 0u; }
        acc0 += (f32x4){bf_lo(v0.x), bf_hi(v0.x), bf_lo(v0.y), bf_hi(v0.y)};
        acc1 += (f32x4){bf_lo(v1.x), bf_hi(v1.x), bf_lo(v1.y), bf_hi(v1.y)};
      }
    }
    f32x4 a = acc0 + acc1;
#pragma unroll
    for (int k = 0; k < 4; ++k) {
      a[k] += __shfl_xor(a[k], 8);
      a[k] += __shfl_xor(a[k], 16);
      a[k] += __shfl_xor(a[k], 32);
    }
    if (lane < 8) {
      const uint2 own = hp2[(unsigned)node * 8u + c8];
      a[0] += bf_lo(own.x) * epv; a[1] += bf_hi(own.x) * epv;
      a[2] += bf_lo(own.y) * epv; a[3] += bf_hi(own.y) * epv;
      *(bf16x4*)(acc + (size_t)node * DIM + plane * 32 + c8 * 4) =
          (bf16x4){(bf16_t)a[0], (bf16_t)a[1], (bf16_t)a[2], (bf16_t)a[3]};
    }
  }
}

// ------- Kernel 4: MLP  out = x + silu(acc@W1b^T+b1)@W2b^T + b2 ----------
__global__ __launch_bounds__(256) void k_mlp(
    const bf16_t* __restrict__ acc, const float* __restrict__ x,
    const bf16_t* __restrict__ W1b, const float* __restrict__ b1,
    const bf16_t* __restrict__ W2b, const float* __restrict__ b2,
    float* __restrict__ out) {
  __shared__ __attribute__((aligned(16))) bf16_t interL[16 * 136];
  const int t = threadIdx.x, lane = t & 63, w = t >> 6;
  const int nodebase = blockIdx.x * 16;
  const int l15 = lane & 15, lq = lane >> 4;

  bf16x8 af[4];
#pragma unroll
  for (int ks = 0; ks < 4; ++ks)
    af[ks] = *(const bf16x8*)(acc + (size_t)(nodebase + l15) * DIM + ks * 32 + lq * 8);

  // GEMM1
  f32x4 c1[2] = {};
#pragma unroll
  for (int cbh = 0; cbh < 2; ++cbh) {
    const int cb = w * 2 + cbh;
    const bf16_t* wrow = W1b + (size_t)(cb * 16 + l15) * DIM;
#pragma unroll
    for (int ks = 0; ks < 4; ++ks) {
      const bf16x8 bf = *(const bf16x8*)(wrow + ks * 32 + lq * 8);
      c1[cbh] = __builtin_amdgcn_mfma_f32_16x16x32_bf16(af[ks], bf, c1[cbh], 0, 0, 0);
    }
  }

  // bias + SiLU -> interL
#pragma unroll
  for (int cbh = 0; cbh < 2; ++cbh) {
    const int cb = w * 2 + cbh;
    const float b1v = b1[cb * 16 + l15];
#pragma unroll
    for (int r = 0; r < 4; ++r) {
      float v = c1[cbh][r] + b1v;
      v = v / (1.0f + __expf(-v));
      interL[(lq * 4 + r) * 136 + cb * 16 + l15] = (bf16_t)v;
    }
  }
  __syncthreads();

  bf16x8 a2[4];
#pragma unroll
  for (int ks = 0; ks < 4; ++ks)
    a2[ks] = *(const bf16x8*)&interL[l15 * 136 + ks * 32 + lq * 8];

  // GEMM2
  f32x4 c2[2] = {};
#pragma unroll
  for (int cbh = 0; cbh < 2; ++cbh) {
    const int cb = w * 2 + cbh;
    const bf16_t* wrow = W2b + (size_t)(cb * 16 + l15) * DIM;
#pragma unroll
    for (int ks = 0; ks < 4; ++ks) {
      const bf16x8 bf = *(const bf16x8*)(wrow + ks * 32 + lq * 8);
      c2[cbh] = __builtin_amdgcn_mfma_f32_16x16x32_bf16(a2[ks], bf, c2[cbh], 0, 0, 0);
    }
  }

  // epilogue: out = x + c2 + b2
#pragma unroll
  for (int cbh = 0; cbh < 2; ++cbh) {
    const int cb = w * 2 + cbh;
    const int c = cb * 16 + l15;
    const float b2v = b2[c];
#pragma unroll
    for (int r = 0; r < 4; ++r) {
      const size_t row = nodebase + lq * 4 + r;
      out[row * DIM + c] = x[row * DIM + c] + c2[cbh][r] + b2v;
    }
  }
}

extern "C" void kernel_launch(void* const* d_in, const int* in_sizes, int n_in,
                              void* d_out, int out_size, void* d_ws, size_t ws_size,
                              hipStream_t stream) {
  const float* x     = (const float*)d_in[0];
  const int*   erows = (const int*)d_in[1];
  const int*   ecols = (const int*)d_in[2];
  const float* W1    = (const float*)d_in[3];
  const float* b1    = (const float*)d_in[4];
  const float* W2    = (const float*)d_in[5];
  const float* b2    = (const float*)d_in[6];
  const float* gamma = (const float*)d_in[7];
  const float* beta  = (const float*)d_in[8];
  const float* eps   = (const float*)d_in[9];
  float* out = (float*)d_out;

  char* ws = (char*)d_ws;
  bf16_t* hq        = (bf16_t*)(ws);                   // 4 planes x 3.2 MB = 12,800,000 B
  unsigned int* tmp = (unsigned int*)(ws + 12800000);  // 196*16384*4 = 12,845,056 B
  bf16_t* acc       = (bf16_t*)(ws + 12800000);        // overlays tmp (dead after binB)
  int*    cnt       = (int*)(ws + 25645056);           //    153,664 B
  unsigned short* sorted = (unsigned short*)(ws + 25798720); // 2,408,448 B
  int*    nstart    = (int*)(ws + 28207168);           //    200,000 B
  int*    nend      = (int*)(ws + 28407168);           //    200,000 B
  bf16_t* W1b       = (bf16_t*)(ws + 28607168);        //     32,768 B
  bf16_t* W2b       = (bf16_t*)(ws + 28639936);        //     32,768 B

  k_ln_binA<<<NBLKA + 8 + LN_BLOCKS, 256, 0, stream>>>(
      x, gamma, beta, hq, erows, ecols, tmp, cnt, W1, W2, W1b, W2b);
  k_binB<<<NBUCKETS, 256, 0, stream>>>(tmp, cnt, nstart, nend, sorted);
  k_gcs<<<6256, 256, 0, stream>>>(
      (const uint2*)hq, nstart, nend, sorted, eps, acc);
  k_mlp<<<N_NODES / 16, 256, 0, stream>>>(acc, x, W1b, b1, W2b, b2, out);
}

// Round 20
// 82.745 us; speedup vs baseline: 1.4492x; 1.4492x over previous
//
#include <hip/hip_runtime.h>
#include <hip/hip_bf16.h>

#define N_NODES 50000
#define DIM 128
#define N_EDGES 800000
#define NBUCKETS 196      // ceil(50000/256) nodes>>8 buckets
#define BINA_EPB 4096     // edges per binning block
#define NBLKA 196         // ceil(800000/4096) binning blocks
#define SEGCAP 64         // per-(block,bucket) segment capacity (mean 21, sigma 4.6)
#define BSTRIDE_U32 16384 // per-bucket tmp stride in u32 (65536 B)
#define BUCKET_CAP 6144   // per-bucket capacity in sorted (mean 4082, sigma ~64)
#define LN_BLOCKS 12500   // N_NODES/4

typedef __bf16 bf16_t;
typedef bf16_t bf16x2 __attribute__((ext_vector_type(2)));
typedef bf16_t bf16x4 __attribute__((ext_vector_type(4)));
typedef bf16_t bf16x8 __attribute__((ext_vector_type(8)));
typedef float f32x4 __attribute__((ext_vector_type(4)));

__device__ __forceinline__ float bf_lo(unsigned int u) {
  return __uint_as_float(u << 16);
}
__device__ __forceinline__ float bf_hi(unsigned int u) {
  return __uint_as_float(u & 0xffff0000u);
}

// ------- Kernel 1: binA (blocks 0..195) | W->bf16 (196..203) | LayerNorm --
__global__ __launch_bounds__(256) void k_ln_binA(
    const float* __restrict__ x, const float* __restrict__ gamma,
    const float* __restrict__ beta, bf16_t* __restrict__ h,
    const int* __restrict__ erows, const int* __restrict__ ecols,
    unsigned int* __restrict__ tmp, int* __restrict__ cnt,
    const float* __restrict__ W1, const float* __restrict__ W2,
    bf16_t* __restrict__ W1b, bf16_t* __restrict__ W2b) {
  __shared__ int sh_hist[256];
  __shared__ int sh_cur[256];
  const int t = threadIdx.x;

  if (blockIdx.x < NBLKA) {
    // ---- binning path ----
    const int blk = blockIdx.x;
    sh_hist[t] = 0;
    __syncthreads();
    const int base = blk * BINA_EPB;
    int bkt[16];
    unsigned int pk[16];
#pragma unroll
    for (int i = 0; i < 16; ++i) {
      const int e = base + i * 256 + t;
      if (e < N_EDGES) {
        const int d = erows[e];
        bkt[i] = d >> 8;
        pk[i] = ((unsigned int)(d & 255) << 16) | (unsigned int)ecols[e];
        atomicAdd(&sh_hist[bkt[i]], 1);
      } else {
        bkt[i] = -1;
      }
    }
    __syncthreads();
    if (t < NBUCKETS) cnt[t * NBLKA + blk] = min(sh_hist[t], SEGCAP);
    sh_cur[t] = 0;
    __syncthreads();
#pragma unroll
    for (int i = 0; i < 16; ++i) {
      if (bkt[i] >= 0) {
        const int pos = atomicAdd(&sh_cur[bkt[i]], 1);
        if (pos < SEGCAP)
          tmp[(size_t)bkt[i] * BSTRIDE_U32 + blk * SEGCAP + pos] = pk[i];
      }
    }
    return;
  }

  if (blockIdx.x < NBLKA + 8) {
    // ---- weight fp32 -> bf16 conversion (W1: 4 blocks, W2: 4 blocks) ----
    const int wid = blockIdx.x - NBLKA;
    const float* src = (wid < 4) ? W1 : W2;
    bf16_t* dst = (wid < 4) ? W1b : W2b;
    const int off = (wid & 3) * 4096 + t * 16;
#pragma unroll
    for (int k = 0; k < 16; k += 4) {
      const float4 u = *(const float4*)(src + off + k);
      *(bf16x4*)(dst + off + k) =
          (bf16x4){(bf16_t)u.x, (bf16_t)u.y, (bf16_t)u.z, (bf16_t)u.w};
    }
    return;
  }

  // ---- LayerNorm path ----
  const int lane = t & 63;
  const int row  = (blockIdx.x - NBLKA - 8) * 4 + (t >> 6);
  const float2 v = *(const float2*)(x + (size_t)row * DIM + lane * 2);
  float s  = v.x + v.y;
  float ss = v.x * v.x + v.y * v.y;
#pragma unroll
  for (int d = 1; d < 64; d <<= 1) {
    s  += __shfl_xor(s, d);
    ss += __shfl_xor(ss, d);
  }
  const float mu   = s * (1.0f / 128.0f);
  const float var  = ss * (1.0f / 128.0f) - mu * mu;
  const float rstd = rsqrtf(var + 1e-5f);
  const float2 g = *(const float2*)(gamma + lane * 2);
  const float2 b = *(const float2*)(beta + lane * 2);
  const float h0 = (v.x - mu) * rstd * g.x + b.x;
  const float h1 = (v.y - mu) * rstd * g.y + b.y;
  *(bf16x2*)(h + (size_t)row * DIM + lane * 2) = (bf16x2){(bf16_t)h0, (bf16_t)h1};
}

// ------- Kernel 2: within-bucket placement -> nstart/nend + sorted(u16) ---
__global__ __launch_bounds__(256) void k_binB(
    const unsigned int* __restrict__ tmp, const int* __restrict__ cnt,
    int* __restrict__ nstart, int* __restrict__ nend,
    unsigned short* __restrict__ sorted) {
  __shared__ unsigned int stage[BUCKET_CAP];
  __shared__ int sh_cnt[256];
  __shared__ int sh_cur[256];
  __shared__ int wsum[4];
  const int b = blockIdx.x, t = threadIdx.x;
  const int lane = t & 63, w = t >> 6;

  // segment counts + exclusive scan -> stage offsets
  const int c = (t < NBLKA) ? cnt[b * NBLKA + t] : 0;
  int v = c;
#pragma unroll
  for (int d = 1; d < 64; d <<= 1) {
    const int n = __shfl_up(v, d);
    if (lane >= d) v += n;
  }
  if (lane == 63) wsum[w] = v;
  __syncthreads();
  int woff = 0;
  for (int k = 0; k < w; ++k) woff += wsum[k];
  const int soff = v + woff - c;
  int total = wsum[0] + wsum[1] + wsum[2] + wsum[3];
  if (total > BUCKET_CAP) total = BUCKET_CAP;

  // stage this bucket's edges into LDS
  if (c > 0) {
    const unsigned int* seg = tmp + (size_t)b * BSTRIDE_U32 + t * SEGCAP;
    for (int j = 0; j < c; ++j) {
      const int p = soff + j;
      if (p < BUCKET_CAP) stage[p] = seg[j];
    }
  }
  __syncthreads();

  // per-node histogram
  sh_cnt[t] = 0;
  __syncthreads();
  for (int e = t; e < total; e += 256)
    atomicAdd(&sh_cnt[stage[e] >> 16], 1);
  __syncthreads();

  // per-node exclusive scan -> starts
  const int val = sh_cnt[t];
  int v2 = val;
#pragma unroll
  for (int d = 1; d < 64; d <<= 1) {
    const int n = __shfl_up(v2, d);
    if (lane >= d) v2 += n;
  }
  __syncthreads();
  if (lane == 63) wsum[w] = v2;
  __syncthreads();
  int woff2 = 0;
  for (int k = 0; k < w; ++k) woff2 += wsum[k];
  const int rs = b * BUCKET_CAP;
  const int st = rs + v2 + woff2 - val;
  const int nidx = b * 256 + t;
  if (nidx < N_NODES) { nstart[nidx] = st; nend[nidx] = st + val; }
  sh_cur[t] = st;
  __syncthreads();

  // place
  for (int e = t; e < total; e += 256) {
    const unsigned int pv = stage[e];
    const int pos = atomicAdd(&sh_cur[pv >> 16], 1);
    sorted[pos] = (unsigned short)(pv & 0xffffu);
  }
}

// ------- Kernel 3 (fused): gather + MLP, 16 nodes/block ------------------
// 3125 blocks x 256 threads. Wave w gathers nodes [4w,4w+4) (shfl/half-wave
// inner loop, 8 edges per batch, 4 independent uint2 loads in flight).
// Then wave w computes the dual GEMM for ALL 16 rows x cols [32w,32w+32),
// intermediate via interL. Weights streamed from global bf16 (L2-resident).
__global__ __launch_bounds__(256) void k_gm(
    const uint2* __restrict__ h4, const int* __restrict__ nstart,
    const int* __restrict__ nend, const unsigned short* __restrict__ sorted,
    const float* __restrict__ epsp, const float* __restrict__ x,
    const bf16_t* __restrict__ W1b, const float* __restrict__ b1,
    const bf16_t* __restrict__ W2b, const float* __restrict__ b2,
    float* __restrict__ out) {
  __shared__ __attribute__((aligned(16))) bf16_t accL[16 * 136];
  __shared__ __attribute__((aligned(16))) bf16_t interL[16 * 136];
  const int t = threadIdx.x, lane = t & 63, w = t >> 6;
  const int half = lane >> 5, l31 = lane & 31;
  const int nodebase = blockIdx.x * 16;
  const float epv = 1.0f + epsp[0];

  // ---- gather: wave w -> local nodes [4w, 4w+4) ----
  for (int i = 0; i < 4; ++i) {
    const int n = w * 4 + i;
    const int gnode = nodebase + n;
    const int s = nstart[gnode], e = nend[gnode];
    f32x4 a0 = {0.f, 0.f, 0.f, 0.f};
    f32x4 a1 = {0.f, 0.f, 0.f, 0.f};
    f32x4 a2v = {0.f, 0.f, 0.f, 0.f};
    f32x4 a3 = {0.f, 0.f, 0.f, 0.f};
    for (int base = s; base < e; base += 64) {
      const int cnt2 = e - base;
      const int m = cnt2 < 64 ? cnt2 : 64;
      const int myidx = (lane < m) ? (int)sorted[base + lane] : 0;
      for (int j = 0; j < m; j += 8) {
        const int o0 = j + half;
        const int o1 = j + 2 + half;
        const int o2 = j + 4 + half;
        const int o3 = j + 6 + half;
        const int s0 = __shfl(myidx, o0);
        const int s1 = __shfl(myidx, o1);
        const int s2 = __shfl(myidx, o2);
        const int s3 = __shfl(myidx, o3);
        uint2 v0 = h4[(size_t)s0 * 32 + l31];
        uint2 v1 = h4[(size_t)s1 * 32 + l31];
        uint2 v2 = h4[(size_t)s2 * 32 + l31];
        uint2 v3 = h4[(size_t)s3 * 32 + l31];
        if (o0 >= m) { v0.x = 0u; v0.y = 0u; }
        if (o1 >= m) { v1.x = 0u; v1.y = 0u; }
        if (o2 >= m) { v2.x = 0u; v2.y = 0u; }
        if (o3 >= m) { v3.x = 0u; v3.y = 0u; }
        a0[0] += bf_lo(v0.x); a0[1] += bf_hi(v0.x);
        a0[2] += bf_lo(v0.y); a0[3] += bf_hi(v0.y);
        a1[0] += bf_lo(v1.x); a1[1] += bf_hi(v1.x);
        a1[2] += bf_lo(v1.y); a1[3] += bf_hi(v1.y);
        a2v[0] += bf_lo(v2.x); a2v[1] += bf_hi(v2.x);
        a2v[2] += bf_lo(v2.y); a2v[3] += bf_hi(v2.y);
        a3[0] += bf_lo(v3.x); a3[1] += bf_hi(v3.x);
        a3[2] += bf_lo(v3.y); a3[3] += bf_hi(v3.y);
      }
    }
    f32x4 tt = (a0 + a1) + (a2v + a3);
#pragma unroll
    for (int k = 0; k < 4; ++k) tt[k] += __shfl_xor(tt[k], 32);
    if (half == 0) {
      const uint2 hv = h4[(size_t)gnode * 32 + l31];
      tt[0] += bf_lo(hv.x) * epv; tt[1] += bf_hi(hv.x) * epv;
      tt[2] += bf_lo(hv.y) * epv; tt[3] += bf_hi(hv.y) * epv;
      *(bf16x4*)&accL[n * 136 + l31 * 4] =
          (bf16x4){(bf16_t)tt[0], (bf16_t)tt[1], (bf16_t)tt[2], (bf16_t)tt[3]};
    }
  }
  __syncthreads();

  // ---- MLP: wave w -> all 16 rows, output cols [32w, 32w+32) ----
  const int l15 = lane & 15, lq = lane >> 4;

  bf16x8 af[4];
#pragma unroll
  for (int ks = 0; ks < 4; ++ks)
    af[ks] = *(const bf16x8*)&accL[l15 * 136 + ks * 32 + lq * 8];

  // GEMM1
  f32x4 c1[2] = {};
#pragma unroll
  for (int cbh = 0; cbh < 2; ++cbh) {
    const int cb = w * 2 + cbh;
    const bf16_t* wrow = W1b + (size_t)(cb * 16 + l15) * DIM;
#pragma unroll
    for (int ks = 0; ks < 4; ++ks) {
      const bf16x8 bf = *(const bf16x8*)(wrow + ks * 32 + lq * 8);
      c1[cbh] = __builtin_amdgcn_mfma_f32_16x16x32_bf16(af[ks], bf, c1[cbh], 0, 0, 0);
    }
  }

  // bias + SiLU -> interL
#pragma unroll
  for (int cbh = 0; cbh < 2; ++cbh) {
    const int cb = w * 2 + cbh;
    const float b1v = b1[cb * 16 + l15];
#pragma unroll
    for (int r = 0; r < 4; ++r) {
      float v = c1[cbh][r] + b1v;
      v = v / (1.0f + __expf(-v));
      interL[(lq * 4 + r) * 136 + cb * 16 + l15] = (bf16_t)v;
    }
  }
  __syncthreads();

  bf16x8 a2[4];
#pragma unroll
  for (int ks = 0; ks < 4; ++ks)
    a2[ks] = *(const bf16x8*)&interL[l15 * 136 + ks * 32 + lq * 8];

  // GEMM2
  f32x4 c2[2] = {};
#pragma unroll
  for (int cbh = 0; cbh < 2; ++cbh) {
    const int cb = w * 2 + cbh;
    const bf16_t* wrow = W2b + (size_t)(cb * 16 + l15) * DIM;
#pragma unroll
    for (int ks = 0; ks < 4; ++ks) {
      const bf16x8 bf = *(const bf16x8*)(wrow + ks * 32 + lq * 8);
      c2[cbh] = __builtin_amdgcn_mfma_f32_16x16x32_bf16(a2[ks], bf, c2[cbh], 0, 0, 0);
    }
  }

  // epilogue: out = x + c2 + b2
#pragma unroll
  for (int cbh = 0; cbh < 2; ++cbh) {
    const int cb = w * 2 + cbh;
    const int c = cb * 16 + l15;
    const float b2v = b2[c];
#pragma unroll
    for (int r = 0; r < 4; ++r) {
      const size_t row = nodebase + lq * 4 + r;
      out[row * DIM + c] = x[row * DIM + c] + c2[cbh][r] + b2v;
    }
  }
}

extern "C" void kernel_launch(void* const* d_in, const int* in_sizes, int n_in,
                              void* d_out, int out_size, void* d_ws, size_t ws_size,
                              hipStream_t stream) {
  const float* x     = (const float*)d_in[0];
  const int*   erows = (const int*)d_in[1];
  const int*   ecols = (const int*)d_in[2];
  const float* W1    = (const float*)d_in[3];
  const float* b1    = (const float*)d_in[4];
  const float* W2    = (const float*)d_in[5];
  const float* b2    = (const float*)d_in[6];
  const float* gamma = (const float*)d_in[7];
  const float* beta  = (const float*)d_in[8];
  const float* eps   = (const float*)d_in[9];
  float* out = (float*)d_out;

  char* ws = (char*)d_ws;
  bf16_t* h         = (bf16_t*)(ws);                   // 12,800,000 B
  unsigned int* tmp = (unsigned int*)(ws + 12800000);  // 196*16384*4 = 12,845,056 B
  int*    cnt       = (int*)(ws + 25645056);           //    153,664 B
  unsigned short* sorted = (unsigned short*)(ws + 25798720); // 2,408,448 B
  int*    nstart    = (int*)(ws + 28207168);           //    200,000 B
  int*    nend      = (int*)(ws + 28407168);           //    200,000 B
  bf16_t* W1b       = (bf16_t*)(ws + 28607168);        //     32,768 B
  bf16_t* W2b       = (bf16_t*)(ws + 28639936);        //     32,768 B

  k_ln_binA<<<NBLKA + 8 + LN_BLOCKS, 256, 0, stream>>>(
      x, gamma, beta, h, erows, ecols, tmp, cnt, W1, W2, W1b, W2b);
  k_binB<<<NBUCKETS, 256, 0, stream>>>(tmp, cnt, nstart, nend, sorted);
  k_gm<<<N_NODES / 16, 256, 0, stream>>>(
      (const uint2*)h, nstart, nend, sorted, eps, x, W1b, b1, W2b, b2, out);
}